// Round 4
// baseline (669.612 us; speedup 1.0000x reference)
//
#include <hip/hip_runtime.h>

#define B_DIM 256
#define I_DIM 128
#define O_DIM 128
#define H_DIM 32
#define F_DIM 7
#define ICHUNK 8
#define NCHUNK (I_DIM / ICHUNK)   // 16

// Pre-kernel: feat[i][b][8] = {x, sin x, sin 2x, sin 4x, cos x, cos 2x, cos 4x, pad}
// 1 MB total, L2-resident; computed ONCE instead of 512x redundantly.
__global__ void feat_kernel(const float* __restrict__ x, float* __restrict__ feat) {
    const int i = blockIdx.x;
    const int b = threadIdx.x;
    float xv = x[(size_t)b * I_DIM + i];
    float s1 = __sinf(xv), c1 = __cosf(xv);
    float s2 = 2.f * s1 * c1, c2 = 1.f - 2.f * s1 * s1;
    float s4 = 2.f * s2 * c2, c4 = 1.f - 2.f * s2 * s2;
    float4* p = reinterpret_cast<float4*>(feat + ((size_t)i * B_DIM + b) * 8);
    p[0] = make_float4(xv, s1, s2, s4);
    p[1] = make_float4(c1, c2, c4, 0.0f);
}

// Main: block = (o, ichunk). hs = tid>>6 (4 h-slices of 8), bg = tid&63,
// thread covers b = bg + 64k (k=0..3) so each LDS weight read feeds 4 FMAs.
// launch_bounds(256,4): VGPR cap 128 — (256,8) capped at 32 and SPILLED
// (R2: 137 MB scratch writes). Do not tighten this again.
// R4: explicit register double-buffer on feat loads — R3 showed VALUBusy 65%
// with VGPR=60 (no pipeline): each il started with a dependent L2-load bubble.
template <bool USE_FEAT>
__global__ __launch_bounds__(256, 4)
void fcnkan_main(const float* __restrict__ feat,
                 const float* __restrict__ x,
                 const float* __restrict__ W1,
                 const float* __restrict__ W2,
                 const float* __restrict__ B1,
                 const float* __restrict__ B2,
                 float* __restrict__ out) {
    __shared__ float w1b1[ICHUNK * H_DIM * 8];   // [il][h][8]: w0..w6, B1 in slot 7
    __shared__ float w2s[ICHUNK * H_DIM];
    __shared__ float b2s[ICHUNK];
    __shared__ float red[4][B_DIM];

    const int tid = threadIdx.x;
    const int o   = blockIdx.x;
    const int ic0 = blockIdx.y * ICHUNK;

    for (int e = tid; e < ICHUNK * H_DIM * F_DIM; e += 256) {
        int il = e / (H_DIM * F_DIM);
        int r  = e - il * (H_DIM * F_DIM);
        int h  = r / F_DIM;
        int f  = r - h * F_DIM;
        w1b1[(il * H_DIM + h) * 8 + f] =
            W1[(size_t)((ic0 + il) * O_DIM + o) * (H_DIM * F_DIM) + r];
    }
    for (int e = tid; e < ICHUNK * H_DIM; e += 256) {
        int il = e >> 5, h = e & 31;
        int io = (ic0 + il) * O_DIM + o;
        w1b1[(il * H_DIM + h) * 8 + 7] = B1[io * H_DIM + h];
        w2s[e]                         = W2[io * H_DIM + h];
    }
    if (tid < ICHUNK) b2s[tid] = B2[(ic0 + tid) * O_DIM + o];
    __syncthreads();

    const int hs = tid >> 6;
    const int bg = tid & 63;

    float acc[4] = {0.f, 0.f, 0.f, 0.f};

    // ---- feature fetch helper (registers) ----
    float4 fa_cur[4], fb_cur[4], fa_nxt[4], fb_nxt[4];

    const float4* fp0 = reinterpret_cast<const float4*>(feat + ((size_t)ic0 * B_DIM) * 8);

    if (USE_FEAT) {
        #pragma unroll
        for (int k = 0; k < 4; ++k) {
            fa_cur[k] = fp0[(bg + 64 * k) * 2];
            fb_cur[k] = fp0[(bg + 64 * k) * 2 + 1];
        }
    } else {
        #pragma unroll
        for (int k = 0; k < 4; ++k) {
            float xv = x[(size_t)(bg + 64 * k) * I_DIM + ic0];
            float s1 = __sinf(xv), c1 = __cosf(xv);
            float s2 = 2.f * s1 * c1, c2 = 1.f - 2.f * s1 * s1;
            float s4 = 2.f * s2 * c2, c4 = 1.f - 2.f * s2 * s2;
            fa_cur[k] = make_float4(xv, s1, s2, s4);
            fb_cur[k] = make_float4(c1, c2, c4, 0.f);
        }
    }

    #pragma unroll
    for (int il = 0; il < ICHUNK; ++il) {
        // prefetch next il's features while computing this one
        if (il + 1 < ICHUNK) {
            if (USE_FEAT) {
                const float4* fpn = reinterpret_cast<const float4*>(
                    feat + ((size_t)(ic0 + il + 1) * B_DIM) * 8);
                #pragma unroll
                for (int k = 0; k < 4; ++k) {
                    fa_nxt[k] = fpn[(bg + 64 * k) * 2];
                    fb_nxt[k] = fpn[(bg + 64 * k) * 2 + 1];
                }
            } else {
                #pragma unroll
                for (int k = 0; k < 4; ++k) {
                    float xv = x[(size_t)(bg + 64 * k) * I_DIM + ic0 + il + 1];
                    float s1 = __sinf(xv), c1 = __cosf(xv);
                    float s2 = 2.f * s1 * c1, c2 = 1.f - 2.f * s1 * s1;
                    float s4 = 2.f * s2 * c2, c4 = 1.f - 2.f * s2 * s2;
                    fa_nxt[k] = make_float4(xv, s1, s2, s4);
                    fb_nxt[k] = make_float4(c1, c2, c4, 0.f);
                }
            }
        }

        const float4* wrow  = reinterpret_cast<const float4*>(w1b1 + il * H_DIM * 8);
        const float*  w2row = w2s + il * H_DIM + hs * 8;
        #pragma unroll
        for (int h = 0; h < 8; ++h) {
            float4 wa  = wrow[(hs * 8 + h) * 2];
            float4 wb  = wrow[(hs * 8 + h) * 2 + 1];   // wb.w = B1 -> dot init
            float  w2v = w2row[h];
            #pragma unroll
            for (int k = 0; k < 4; ++k) {
                float z = fmaf(wa.x, fa_cur[k].x, wb.w);   // w0*x + B1
                z = fmaf(wa.y, fa_cur[k].y, z);
                z = fmaf(wa.z, fa_cur[k].z, z);
                z = fmaf(wa.w, fa_cur[k].w, z);
                z = fmaf(wb.x, fb_cur[k].x, z);
                z = fmaf(wb.y, fb_cur[k].y, z);
                z = fmaf(wb.z, fb_cur[k].z, z);
                float ev = __expf(-z);
                float sg = __builtin_amdgcn_rcpf(1.f + ev);
                acc[k] = fmaf(z * sg, w2v, acc[k]);
            }
        }

        if (il + 1 < ICHUNK) {
            #pragma unroll
            for (int k = 0; k < 4; ++k) { fa_cur[k] = fa_nxt[k]; fb_cur[k] = fb_nxt[k]; }
        }
    }

    #pragma unroll
    for (int k = 0; k < 4; ++k) red[hs][bg + 64 * k] = acc[k];
    __syncthreads();

    float b2c = 0.f;
    #pragma unroll
    for (int il = 0; il < ICHUNK; ++il) b2c += b2s[il];

    float total = red[0][tid] + red[1][tid] + red[2][tid] + red[3][tid] + b2c;
    atomicAdd(&out[(size_t)tid * O_DIM + o], total);
}

extern "C" void kernel_launch(void* const* d_in, const int* in_sizes, int n_in,
                              void* d_out, int out_size, void* d_ws, size_t ws_size,
                              hipStream_t stream) {
    const float* x  = (const float*)d_in[0];
    const float* W1 = (const float*)d_in[1];
    const float* W2 = (const float*)d_in[2];
    const float* B1 = (const float*)d_in[3];
    const float* B2 = (const float*)d_in[4];
    float* out  = (float*)d_out;
    float* feat = (float*)d_ws;

    const size_t feat_bytes = (size_t)I_DIM * B_DIM * 8 * sizeof(float); // 1 MiB
    const bool use_feat = (ws_size >= feat_bytes);  // launch-invariant -> graph-safe

    hipMemsetAsync(out, 0, (size_t)out_size * sizeof(float), stream);
    dim3 grid(O_DIM, NCHUNK);
    if (use_feat) {
        feat_kernel<<<I_DIM, B_DIM, 0, stream>>>(x, feat);
        fcnkan_main<true><<<grid, 256, 0, stream>>>(feat, x, W1, W2, B1, B2, out);
    } else {
        fcnkan_main<false><<<grid, 256, 0, stream>>>(feat, x, W1, W2, B1, B2, out);
    }
}

// Round 5
// 237.695 us; speedup vs baseline: 2.8171x; 2.8171x over previous
//
#include <hip/hip_runtime.h>

#define B_DIM 256
#define I_DIM 128
#define O_DIM 128
#define H_DIM 32
#define F_DIM 7
#define ICHUNK 8
#define NCHUNK (I_DIM / ICHUNK)   // 16

// Pre-kernel: feat[i][b][8] = {x, sin x, sin 2x, sin 4x, cos x, cos 2x, cos 4x, pad}
// 1 MB total, L2-resident; computed ONCE instead of 512x redundantly.
__global__ void feat_kernel(const float* __restrict__ x, float* __restrict__ feat) {
    const int i = blockIdx.x;
    const int b = threadIdx.x;
    float xv = x[(size_t)b * I_DIM + i];
    float s1 = __sinf(xv), c1 = __cosf(xv);
    float s2 = 2.f * s1 * c1, c2 = 1.f - 2.f * s1 * s1;
    float s4 = 2.f * s2 * c2, c4 = 1.f - 2.f * s2 * s2;
    float4* p = reinterpret_cast<float4*>(feat + ((size_t)i * B_DIM + b) * 8);
    p[0] = make_float4(xv, s1, s2, s4);
    p[1] = make_float4(c1, c2, c4, 0.0f);
}

// Main: block = (o, ichunk). hs = tid>>6 (4 h-slices of 8), bg = tid&63,
// thread covers b = bg + 64k (k=0..3) so each LDS weight read feeds 4 FMAs.
//
// REGISTER-PRESSURE HISTORY (do not regress):
//   (256,8) -> VGPR cap 64, compiler hit 32, SPILLED: 137 MB scratch (R2).
//   explicit fa_nxt/fb_nxt double-buffer + unrolled il loop -> VGPR 64,
//     SPILLED: 1.2 GB scratch writes, 625 us (R4).
//   (256,4), rolled il loop, no prefetch arrays -> VGPR 60, clean (R3).
// R5: (256,6) = VGPR cap 85 (safe for the 60-VGPR body) -> 6 blocks/CU of
// TLP to hide the per-il L2 feat-load latency, instead of ILP pipelining.
template <bool USE_FEAT>
__global__ __launch_bounds__(256, 6)
void fcnkan_main(const float* __restrict__ feat,
                 const float* __restrict__ x,
                 const float* __restrict__ W1,
                 const float* __restrict__ W2,
                 const float* __restrict__ B1,
                 const float* __restrict__ B2,
                 float* __restrict__ out) {
    __shared__ float w1b1[ICHUNK * H_DIM * 8];   // [il][h][8]: w0..w6, B1 in slot 7
    __shared__ float w2s[ICHUNK * H_DIM];
    __shared__ float b2s[ICHUNK];
    __shared__ float red[4][B_DIM];

    const int tid = threadIdx.x;
    const int o   = blockIdx.x;
    const int ic0 = blockIdx.y * ICHUNK;

    for (int e = tid; e < ICHUNK * H_DIM * F_DIM; e += 256) {
        int il = e / (H_DIM * F_DIM);
        int r  = e - il * (H_DIM * F_DIM);
        int h  = r / F_DIM;
        int f  = r - h * F_DIM;
        w1b1[(il * H_DIM + h) * 8 + f] =
            W1[(size_t)((ic0 + il) * O_DIM + o) * (H_DIM * F_DIM) + r];
    }
    for (int e = tid; e < ICHUNK * H_DIM; e += 256) {
        int il = e >> 5, h = e & 31;
        int io = (ic0 + il) * O_DIM + o;
        w1b1[(il * H_DIM + h) * 8 + 7] = B1[io * H_DIM + h];
        w2s[e]                         = W2[io * H_DIM + h];
    }
    if (tid < ICHUNK) b2s[tid] = B2[(ic0 + tid) * O_DIM + o];
    __syncthreads();

    const int hs = tid >> 6;
    const int bg = tid & 63;

    float acc[4] = {0.f, 0.f, 0.f, 0.f};

    for (int il = 0; il < ICHUNK; ++il) {
        float4 fa[4], fb[4];
        if (USE_FEAT) {
            const float4* fp = reinterpret_cast<const float4*>(
                feat + ((size_t)(ic0 + il) * B_DIM) * 8);
            #pragma unroll
            for (int k = 0; k < 4; ++k) {
                fa[k] = fp[(bg + 64 * k) * 2];
                fb[k] = fp[(bg + 64 * k) * 2 + 1];
            }
        } else {
            #pragma unroll
            for (int k = 0; k < 4; ++k) {
                float xv = x[(size_t)(bg + 64 * k) * I_DIM + ic0 + il];
                float s1 = __sinf(xv), c1 = __cosf(xv);
                float s2 = 2.f * s1 * c1, c2 = 1.f - 2.f * s1 * s1;
                float s4 = 2.f * s2 * c2, c4 = 1.f - 2.f * s2 * s2;
                fa[k] = make_float4(xv, s1, s2, s4);
                fb[k] = make_float4(c1, c2, c4, 0.f);
            }
        }
        const float4* wrow  = reinterpret_cast<const float4*>(w1b1 + il * H_DIM * 8);
        const float*  w2row = w2s + il * H_DIM + hs * 8;
        #pragma unroll
        for (int h = 0; h < 8; ++h) {
            float4 wa  = wrow[(hs * 8 + h) * 2];
            float4 wb  = wrow[(hs * 8 + h) * 2 + 1];   // wb.w = B1 -> dot init
            float  w2v = w2row[h];
            #pragma unroll
            for (int k = 0; k < 4; ++k) {
                float z = fmaf(wa.x, fa[k].x, wb.w);   // w0*x + B1
                z = fmaf(wa.y, fa[k].y, z);
                z = fmaf(wa.z, fa[k].z, z);
                z = fmaf(wa.w, fa[k].w, z);
                z = fmaf(wb.x, fb[k].x, z);
                z = fmaf(wb.y, fb[k].y, z);
                z = fmaf(wb.z, fb[k].z, z);
                float ev = __expf(-z);
                float sg = __builtin_amdgcn_rcpf(1.f + ev);
                acc[k] = fmaf(z * sg, w2v, acc[k]);
            }
        }
    }

    #pragma unroll
    for (int k = 0; k < 4; ++k) red[hs][bg + 64 * k] = acc[k];
    __syncthreads();

    float b2c = 0.f;
    #pragma unroll
    for (int il = 0; il < ICHUNK; ++il) b2c += b2s[il];

    float total = red[0][tid] + red[1][tid] + red[2][tid] + red[3][tid] + b2c;
    atomicAdd(&out[(size_t)tid * O_DIM + o], total);
}

extern "C" void kernel_launch(void* const* d_in, const int* in_sizes, int n_in,
                              void* d_out, int out_size, void* d_ws, size_t ws_size,
                              hipStream_t stream) {
    const float* x  = (const float*)d_in[0];
    const float* W1 = (const float*)d_in[1];
    const float* W2 = (const float*)d_in[2];
    const float* B1 = (const float*)d_in[3];
    const float* B2 = (const float*)d_in[4];
    float* out  = (float*)d_out;
    float* feat = (float*)d_ws;

    const size_t feat_bytes = (size_t)I_DIM * B_DIM * 8 * sizeof(float); // 1 MiB
    const bool use_feat = (ws_size >= feat_bytes);  // launch-invariant -> graph-safe

    hipMemsetAsync(out, 0, (size_t)out_size * sizeof(float), stream);
    dim3 grid(O_DIM, NCHUNK);
    if (use_feat) {
        feat_kernel<<<I_DIM, B_DIM, 0, stream>>>(x, feat);
        fcnkan_main<true><<<grid, 256, 0, stream>>>(feat, x, W1, W2, B1, B2, out);
    } else {
        fcnkan_main<false><<<grid, 256, 0, stream>>>(feat, x, W1, W2, B1, B2, out);
    }
}

// Round 6
// 137.411 us; speedup vs baseline: 4.8731x; 1.7298x over previous
//
#include <hip/hip_runtime.h>

#define B_DIM 256
#define I_DIM 128
#define O_DIM 128
#define H_DIM 32
#define F_DIM 7
#define ICHUNK 8
#define NCHUNK (I_DIM / ICHUNK)   // 16

// Async global->LDS, 16B/lane, wave-uniform LDS base + lane*16.
#define GLOAD_LDS(g, l) __builtin_amdgcn_global_load_lds( \
    (const __attribute__((address_space(1))) void*)(g),   \
    (__attribute__((address_space(3))) void*)(l), 16, 0, 0)

// Pre-kernel: feat[i][b][8] = {x, sin x, sin 2x, sin 4x, cos x, cos 2x, cos 4x, pad}
// (1 MB, L2-resident). Also zeroes out[] (I_DIM*B_DIM == out_size == 32768),
// replacing the separate hipMemsetAsync dispatch.
__global__ void feat_kernel(const float* __restrict__ x, float* __restrict__ feat,
                            float* __restrict__ out) {
    const int i = blockIdx.x;
    const int b = threadIdx.x;
    float xv = x[(size_t)b * I_DIM + i];
    float s1 = __sinf(xv), c1 = __cosf(xv);
    float s2 = 2.f * s1 * c1, c2 = 1.f - 2.f * s1 * s1;
    float s4 = 2.f * s2 * c2, c4 = 1.f - 2.f * s2 * s2;
    float4* p = reinterpret_cast<float4*>(feat + ((size_t)i * B_DIM + b) * 8);
    p[0] = make_float4(xv, s1, s2, s4);
    p[1] = make_float4(c1, c2, c4, 0.0f);
    out[i * B_DIM + b] = 0.0f;
}

// REGISTER-PRESSURE LAW (measured R2/R4/R5 — do not regress):
//   __launch_bounds__(256, w) => hard VGPR cap = 256/w; compiler SPILLS to meet it.
//   w=8 -> cap 32 (137 MB scratch, R2); w=6 -> cap 40 (456 MB scratch, R5);
//   w=4 -> cap 64, body fits at 60 (clean, R3). Explicit register prefetch
//   arrays also spilled (1.2 GB scratch, R4).
// R6: w=3 (cap 85) — LDS (25.9 KB -> 6 blocks/CU) caps residency anyway, so the
// looser VGPR cap costs nothing and de-risks the added staging code.
// Latency hiding now via async global_load_lds double-buffer (zero data VGPRs).
template <bool USE_FEAT>
__global__ __launch_bounds__(256, 3)
void fcnkan_main(const float* __restrict__ feat,
                 const float* __restrict__ x,
                 const float* __restrict__ W1,
                 const float* __restrict__ W2,
                 const float* __restrict__ B1,
                 const float* __restrict__ B2,
                 float* __restrict__ out) {
    // layout (floats): w1b1[2048] | w2s[256] | b2s[8..63 pad] | fb0[2048] | fb1[2048]
    __shared__ __align__(16) float smem[6464];   // 25856 B
    float* w1b1 = smem;          // [il][h][8]: w0..w6, B1 in slot 7
    float* w2s  = smem + 2048;
    float* b2s  = smem + 2304;
    float* fb0  = smem + 2368;   // byte offset 9472 (16B aligned)
    float* fb1  = smem + 4416;

    const int tid = threadIdx.x;
    const int o   = blockIdx.x;
    const int ic0 = blockIdx.y * ICHUNK;

    for (int e = tid; e < ICHUNK * H_DIM * F_DIM; e += 256) {
        int il = e / (H_DIM * F_DIM);
        int r  = e - il * (H_DIM * F_DIM);
        int h  = r / F_DIM;
        int f  = r - h * F_DIM;
        w1b1[(il * H_DIM + h) * 8 + f] =
            W1[(size_t)((ic0 + il) * O_DIM + o) * (H_DIM * F_DIM) + r];
    }
    for (int e = tid; e < ICHUNK * H_DIM; e += 256) {
        int il = e >> 5, h = e & 31;
        int io = (ic0 + il) * O_DIM + o;
        w1b1[(il * H_DIM + h) * 8 + 7] = B1[io * H_DIM + h];
        w2s[e]                         = W2[io * H_DIM + h];
    }
    if (tid < ICHUNK) b2s[tid] = B2[(ic0 + tid) * O_DIM + o];

    const int hs = tid >> 6;   // h-slice (wave-uniform)
    const int bg = tid & 63;   // lane
    const int wv = hs;         // wave id 0..3

    // prefetch il=0 feat slice (8 KB) into fb0: 8 chunks of 1 KB, 2 per wave
    if (USE_FEAT) {
        const float* src = feat + (size_t)ic0 * (B_DIM * 8);
        #pragma unroll
        for (int t = 0; t < 2; ++t) {
            int c = wv * 2 + t;
            GLOAD_LDS(src + c * 256 + bg * 4, fb0 + c * 256);
        }
    }
    __syncthreads();   // drains staging stores + async prefetch

    float acc[4] = {0.f, 0.f, 0.f, 0.f};

    for (int il = 0; il < ICHUNK; ++il) {
        float* cur = (il & 1) ? fb1 : fb0;
        // async prefetch of il+1 into the other buffer; completed by the
        // barrier at the end of this iteration (after ~1150 cyc of compute).
        if (USE_FEAT && il + 1 < ICHUNK) {
            float* nxt = ((il + 1) & 1) ? fb1 : fb0;
            const float* src = feat + (size_t)(ic0 + il + 1) * (B_DIM * 8);
            #pragma unroll
            for (int t = 0; t < 2; ++t) {
                int c = wv * 2 + t;
                GLOAD_LDS(src + c * 256 + bg * 4, nxt + c * 256);
            }
        }

        float4 fa[4], fb[4];
        if (USE_FEAT) {
            const float4* fp = reinterpret_cast<const float4*>(cur);
            #pragma unroll
            for (int k = 0; k < 4; ++k) {
                fa[k] = fp[(bg + 64 * k) * 2];       // ds_read_b128
                fb[k] = fp[(bg + 64 * k) * 2 + 1];
            }
        } else {
            #pragma unroll
            for (int k = 0; k < 4; ++k) {
                float xv = x[(size_t)(bg + 64 * k) * I_DIM + ic0 + il];
                float s1 = __sinf(xv), c1 = __cosf(xv);
                float s2 = 2.f * s1 * c1, c2 = 1.f - 2.f * s1 * s1;
                float s4 = 2.f * s2 * c2, c4 = 1.f - 2.f * s2 * s2;
                fa[k] = make_float4(xv, s1, s2, s4);
                fb[k] = make_float4(c1, c2, c4, 0.f);
            }
        }

        const float4* wrow  = reinterpret_cast<const float4*>(w1b1 + il * H_DIM * 8);
        const float*  w2row = w2s + il * H_DIM + hs * 8;
        #pragma unroll
        for (int h = 0; h < 8; ++h) {
            float4 wa  = wrow[(hs * 8 + h) * 2];
            float4 wb  = wrow[(hs * 8 + h) * 2 + 1];   // wb.w = B1 -> dot init
            float  w2v = w2row[h];
            #pragma unroll
            for (int k = 0; k < 4; ++k) {
                float z = fmaf(wa.x, fa[k].x, wb.w);   // w0*x + B1
                z = fmaf(wa.y, fa[k].y, z);
                z = fmaf(wa.z, fa[k].z, z);
                z = fmaf(wa.w, fa[k].w, z);
                z = fmaf(wb.x, fb[k].x, z);
                z = fmaf(wb.y, fb[k].y, z);
                z = fmaf(wb.z, fb[k].z, z);
                float ev = __expf(-z);
                float sg = __builtin_amdgcn_rcpf(1.f + ev);
                acc[k] = fmaf(z * sg, w2v, acc[k]);
            }
        }
        __syncthreads();   // reads of cur done + prefetch drained
    }

    // red[4][256] aliases fb0 (featbuf dead after the loop; barrier above)
    float* red = fb0;
    #pragma unroll
    for (int k = 0; k < 4; ++k) red[hs * B_DIM + bg + 64 * k] = acc[k];
    __syncthreads();

    float b2c = 0.f;
    #pragma unroll
    for (int il = 0; il < ICHUNK; ++il) b2c += b2s[il];

    float total = red[tid] + red[B_DIM + tid] + red[2 * B_DIM + tid]
                + red[3 * B_DIM + tid] + b2c;
    atomicAdd(&out[(size_t)tid * O_DIM + o], total);
}

extern "C" void kernel_launch(void* const* d_in, const int* in_sizes, int n_in,
                              void* d_out, int out_size, void* d_ws, size_t ws_size,
                              hipStream_t stream) {
    const float* x  = (const float*)d_in[0];
    const float* W1 = (const float*)d_in[1];
    const float* W2 = (const float*)d_in[2];
    const float* B1 = (const float*)d_in[3];
    const float* B2 = (const float*)d_in[4];
    float* out  = (float*)d_out;
    float* feat = (float*)d_ws;

    const size_t feat_bytes = (size_t)I_DIM * B_DIM * 8 * sizeof(float); // 1 MiB
    const bool use_feat = (ws_size >= feat_bytes);  // launch-invariant -> graph-safe

    dim3 grid(O_DIM, NCHUNK);
    if (use_feat) {
        feat_kernel<<<I_DIM, B_DIM, 0, stream>>>(x, feat, out);  // also zeroes out
        fcnkan_main<true><<<grid, 256, 0, stream>>>(feat, x, W1, W2, B1, B2, out);
    } else {
        hipMemsetAsync(out, 0, (size_t)out_size * sizeof(float), stream);
        fcnkan_main<false><<<grid, 256, 0, stream>>>(feat, x, W1, W2, B1, B2, out);
    }
}

// Round 7
// 126.288 us; speedup vs baseline: 5.3023x; 1.0881x over previous
//
#include <hip/hip_runtime.h>

#define B_DIM 256
#define I_DIM 128
#define O_DIM 128
#define H_DIM 32
#define F_DIM 7
#define ICHUNK 8
#define NCHUNK (I_DIM / ICHUNK)   // 16

// R7 "thread-owns-b" restructure.
// Block = (o, i-chunk); thread tid owns batch row b = tid and computes ALL
// 32 h for each il, accumulating the W2 dot in-register.
//  - features (x, sin/cos + double-angle) computed inline in registers:
//    ~28 cyc per il vs ~1100 cyc of h-loop compute -> feat pre-kernel,
//    workspace, and all feat memory traffic deleted.
//  - weight reads are wave-uniform LDS broadcasts: conflict-free
//    (R6's 3.37M SQ_LDS_BANK_CONFLICT came from 32B/lane-stride b128 reads).
//  - h-sum in-thread -> no red[] LDS, no in-loop barriers (one barrier total).
//
// REGISTER-PRESSURE LAW (measured R2/R4/R5 — do not regress):
//   __launch_bounds__(256, w) => hard VGPR cap 256/w; compiler SPILLS to meet
//   it. w=8 -> 137 MB scratch (R2); w=6 -> 456 MB scratch (R5); w=4 -> cap 64,
//   clean (R3). Explicit big prefetch arrays also spilled (1.2 GB, R4).
//   Here live state ~50 regs -> (256,4) safe; at <=64 VGPR + 9.3 KB LDS the
//   full grid (8 blocks/CU = 8 waves/SIMD) is co-resident.
// #pragma unroll 4 on the h-loop is deliberate: full 32x unroll hoists ~72
// weight regs and would re-trigger the R4 spill pattern.
__global__ __launch_bounds__(256, 4)
void fcnkan_kernel(const float* __restrict__ x,
                   const float* __restrict__ W1,
                   const float* __restrict__ W2,
                   const float* __restrict__ B1,
                   const float* __restrict__ B2,
                   float* __restrict__ out) {
    __shared__ __align__(16) float w1b1[ICHUNK * H_DIM * 8]; // [il][h][8]: w0..w6, B1
    __shared__ float w2s[ICHUNK * H_DIM];
    __shared__ float b2s[ICHUNK];

    const int tid = threadIdx.x;
    const int o   = blockIdx.x;
    const int ic0 = blockIdx.y * ICHUNK;

    // ---- stage weights (coalesced) ----
    for (int e = tid; e < ICHUNK * H_DIM * F_DIM; e += 256) {
        int il = e / (H_DIM * F_DIM);
        int r  = e - il * (H_DIM * F_DIM);
        int h  = r / F_DIM;
        int f  = r - h * F_DIM;
        w1b1[(il * H_DIM + h) * 8 + f] =
            W1[(size_t)((ic0 + il) * O_DIM + o) * (H_DIM * F_DIM) + r];
    }
    for (int e = tid; e < ICHUNK * H_DIM; e += 256) {
        int il = e >> 5, h = e & 31;
        int io = (ic0 + il) * O_DIM + o;
        w1b1[(il * H_DIM + h) * 8 + 7] = B1[io * H_DIM + h];
        w2s[e]                         = W2[io * H_DIM + h];
    }
    if (tid < ICHUNK) b2s[tid] = B2[(ic0 + tid) * O_DIM + o];

    // thread's 8 x values (two float4 loads; ic0 % 8 == 0 -> 16B aligned)
    const float4* xp = reinterpret_cast<const float4*>(x + (size_t)tid * I_DIM + ic0);
    float4 x0 = xp[0], x1 = xp[1];
    float xr[8] = {x0.x, x0.y, x0.z, x0.w, x1.x, x1.y, x1.z, x1.w};

    __syncthreads();

    float acc = 0.f;

    #pragma unroll
    for (int il = 0; il < ICHUNK; ++il) {
        float xv = xr[il];
        float s1 = __sinf(xv), c1 = __cosf(xv);
        float s2 = 2.f * s1 * c1, c2 = 1.f - 2.f * s1 * s1;
        float s4 = 2.f * s2 * c2, c4 = 1.f - 2.f * s2 * s2;

        const float4* wrow  = reinterpret_cast<const float4*>(w1b1 + il * H_DIM * 8);
        const float*  w2row = w2s + il * H_DIM;

        #pragma unroll 4
        for (int h = 0; h < H_DIM; ++h) {
            float4 wa = wrow[h * 2];        // broadcast ds_read_b128 (uniform addr)
            float4 wb = wrow[h * 2 + 1];    // wb.w = B1
            float z = fmaf(wa.x, xv, wb.w);
            z = fmaf(wa.y, s1, z);
            z = fmaf(wa.z, s2, z);
            z = fmaf(wa.w, s4, z);
            z = fmaf(wb.x, c1, z);
            z = fmaf(wb.y, c2, z);
            z = fmaf(wb.z, c4, z);
            float sg = __builtin_amdgcn_rcpf(1.f + __expf(-z));   // sigmoid
            acc = fmaf(z * sg, w2row[h], acc);                    // silu * W2
        }
    }

    float b2c = 0.f;
    #pragma unroll
    for (int il = 0; il < ICHUNK; ++il) b2c += b2s[il];

    atomicAdd(&out[(size_t)tid * O_DIM + o], acc + b2c);
}

extern "C" void kernel_launch(void* const* d_in, const int* in_sizes, int n_in,
                              void* d_out, int out_size, void* d_ws, size_t ws_size,
                              hipStream_t stream) {
    const float* x  = (const float*)d_in[0];
    const float* W1 = (const float*)d_in[1];
    const float* W2 = (const float*)d_in[2];
    const float* B1 = (const float*)d_in[3];
    const float* B2 = (const float*)d_in[4];
    float* out = (float*)d_out;

    hipMemsetAsync(out, 0, (size_t)out_size * sizeof(float), stream);
    dim3 grid(O_DIM, NCHUNK);
    fcnkan_kernel<<<grid, 256, 0, stream>>>(x, W1, W2, B1, B2, out);
}

// Round 8
// 125.650 us; speedup vs baseline: 5.3292x; 1.0051x over previous
//
#include <hip/hip_runtime.h>

#define B_DIM 256
#define I_DIM 128
#define O_DIM 128
#define H_DIM 32
#define F_DIM 7
#define ICHUNK 8
#define NCHUNK (I_DIM / ICHUNK)   // 16

// R8: hybrid of R7 (inline trig, no feat array/pre-kernel) and R3 (thread =
// 4 b x 8 h so each broadcast weight read feeds 4 FMA chains).
// R7 post-mortem: thread-owns-b reads ALL 256 weight floats/il per thread ->
// 4.3 GB of LDS reads ~= 62 us at the 69 TB/s LDS ceiling == measured 64.6 us.
// 4-b amortization cuts DS volume 4x (-> ~17 us), VALU (~34 us) becomes the
// bound again. x is staged through LDS (coalesced global read, transposed
// [il][b] store, conflict-free stride-1 reads) -> zero global loads in loop.
//
// REGISTER-PRESSURE LAW (measured R2/R4/R5 — do not regress):
//   __launch_bounds__(256, w) => hard VGPR cap 256/w; the allocator SPILLS to
//   meet it. w=8 -> 137 MB scratch (R2); w=6 -> 456 MB scratch (R5); w=4 ->
//   cap 64, body fit at 60 (R3, clean). Explicit prefetch arrays spilled (R4).
// R8 body ~= R3's register profile (28 trig regs vs R3's 32 feat regs).
// (256,3) = cap 85: no forced spill; LDS (21.5 KB -> 7 blocks/CU) governs
// occupancy, not the VGPR cap.
__global__ __launch_bounds__(256, 3)
void fcnkan_kernel(const float* __restrict__ x,
                   const float* __restrict__ W1,
                   const float* __restrict__ W2,
                   const float* __restrict__ B1,
                   const float* __restrict__ B2,
                   float* __restrict__ out) {
    __shared__ __align__(16) float w1b1[ICHUNK * H_DIM * 8]; // [il][h][8] w0..w6,B1
    __shared__ float w2s[ICHUNK * H_DIM];                    // [il][h]
    __shared__ float b2s[ICHUNK];
    __shared__ float xs[ICHUNK][B_DIM];                      // [il][b] transposed
    __shared__ float red[4][B_DIM];

    const int tid = threadIdx.x;
    const int o   = blockIdx.x;
    const int ic0 = blockIdx.y * ICHUNK;

    // ---- stage weights (coalesced) ----
    for (int e = tid; e < ICHUNK * H_DIM * F_DIM; e += 256) {
        int il = e / (H_DIM * F_DIM);
        int r  = e - il * (H_DIM * F_DIM);
        int h  = r / F_DIM;
        int f  = r - h * F_DIM;
        w1b1[(il * H_DIM + h) * 8 + f] =
            W1[(size_t)((ic0 + il) * O_DIM + o) * (H_DIM * F_DIM) + r];
    }
    for (int e = tid; e < ICHUNK * H_DIM; e += 256) {
        int il = e >> 5, h = e & 31;
        int io = (ic0 + il) * O_DIM + o;
        w1b1[(il * H_DIM + h) * 8 + 7] = B1[io * H_DIM + h];
        w2s[e]                         = W2[io * H_DIM + h];
    }
    if (tid < ICHUNK) b2s[tid] = B2[(ic0 + tid) * O_DIM + o];

    // ---- stage x: own row, 2x float4 (ic0 % 8 == 0 -> aligned), transpose ----
    {
        const float4* xp = reinterpret_cast<const float4*>(x + (size_t)tid * I_DIM + ic0);
        float4 x0 = xp[0], x1 = xp[1];
        xs[0][tid] = x0.x; xs[1][tid] = x0.y; xs[2][tid] = x0.z; xs[3][tid] = x0.w;
        xs[4][tid] = x1.x; xs[5][tid] = x1.y; xs[6][tid] = x1.z; xs[7][tid] = x1.w;
    }
    __syncthreads();

    const int hs = tid >> 6;   // h-slice: h in [hs*8, hs*8+8)
    const int bg = tid & 63;   // b-group: b = bg + 64k

    float acc[4] = {0.f, 0.f, 0.f, 0.f};

    for (int il = 0; il < ICHUNK; ++il) {
        // inline trig for this thread's 4 b's (in-register features)
        float xv[4], s1[4], c1[4], s2[4], c2[4], s4[4], c4[4];
        #pragma unroll
        for (int k = 0; k < 4; ++k) {
            xv[k] = xs[il][bg + 64 * k];        // stride-1 -> conflict-free
            s1[k] = __sinf(xv[k]);
            c1[k] = __cosf(xv[k]);
            s2[k] = 2.f * s1[k] * c1[k];
            c2[k] = 1.f - 2.f * s1[k] * s1[k];
            s4[k] = 2.f * s2[k] * c2[k];
            c4[k] = 1.f - 2.f * s2[k] * s2[k];
        }

        const float4* wrow  = reinterpret_cast<const float4*>(w1b1 + il * H_DIM * 8);
        const float*  w2row = w2s + il * H_DIM + hs * 8;

        #pragma unroll
        for (int h = 0; h < 8; ++h) {
            float4 wa  = wrow[(hs * 8 + h) * 2];     // wave-uniform broadcast
            float4 wb  = wrow[(hs * 8 + h) * 2 + 1]; // wb.w = B1 -> dot init
            float  w2v = w2row[h];
            #pragma unroll
            for (int k = 0; k < 4; ++k) {
                float z = fmaf(wa.x, xv[k], wb.w);
                z = fmaf(wa.y, s1[k], z);
                z = fmaf(wa.z, s2[k], z);
                z = fmaf(wa.w, s4[k], z);
                z = fmaf(wb.x, c1[k], z);
                z = fmaf(wb.y, c2[k], z);
                z = fmaf(wb.z, c4[k], z);
                float sg = __builtin_amdgcn_rcpf(1.f + __expf(-z));  // sigmoid
                acc[k] = fmaf(z * sg, w2v, acc[k]);                  // silu * W2
            }
        }
    }

    // ---- reduce over the 4 h-slices ----
    #pragma unroll
    for (int k = 0; k < 4; ++k) red[hs][bg + 64 * k] = acc[k];
    __syncthreads();

    float b2c = 0.f;
    #pragma unroll
    for (int il = 0; il < ICHUNK; ++il) b2c += b2s[il];

    float total = red[0][tid] + red[1][tid] + red[2][tid] + red[3][tid] + b2c;
    atomicAdd(&out[(size_t)tid * O_DIM + o], total);
}

extern "C" void kernel_launch(void* const* d_in, const int* in_sizes, int n_in,
                              void* d_out, int out_size, void* d_ws, size_t ws_size,
                              hipStream_t stream) {
    const float* x  = (const float*)d_in[0];
    const float* W1 = (const float*)d_in[1];
    const float* W2 = (const float*)d_in[2];
    const float* B1 = (const float*)d_in[3];
    const float* B2 = (const float*)d_in[4];
    float* out = (float*)d_out;

    hipMemsetAsync(out, 0, (size_t)out_size * sizeof(float), stream);
    dim3 grid(O_DIM, NCHUNK);
    fcnkan_kernel<<<grid, 256, 0, stream>>>(x, W1, W2, B1, B2, out);
}

// Round 9
// 123.406 us; speedup vs baseline: 5.4261x; 1.0182x over previous
//
#include <hip/hip_runtime.h>
#include <hip/hip_bf16.h>

#define B_DIM 256
#define I_DIM 128
#define O_DIM 128
#define H_DIM 32
#define F_DIM 7
#define ICHUNK 16
#define NCHUNK (I_DIM / ICHUNK)   // 8

typedef __attribute__((ext_vector_type(8))) short short8;   // 8 bf16 (4 VGPRs)
typedef __attribute__((ext_vector_type(4))) float float4v;  // MFMA C/D

__device__ inline short bf16s(float v) {
    union { __hip_bfloat16 h; short s; } u;
    u.h = __float2bfloat16(v);
    return u.s;
}

// R9: einsum1 on the matrix pipe.
// Per (i, o): z[b,h] = feat[b,f] @ W1[h,f]^T + B1[h]  as mfma_f32_16x16x32_bf16
// with f occupying k=0..6 of quad 0 (quads 1-3 zero — K-padding costs only
// matrix-pipe cycles, which are otherwise idle: MfmaUtil was 0.0 in R1-R8).
//  - A-frag built IN REGISTERS from inline trig (A[m=lane&15][k=quad*8+j]):
//    no feat array, no LDS, no barriers anywhere in the kernel.
//  - B1 folded into the MFMA C-initializer (col=lane&15 = h).
//  - C/D layout (m89-verified): col=lane&15=h, row=quad*4+reg=b. silu+W2 dot
//    straight from accumulator regs; h-sum via 4 shfl_xor steps (lanes of one
//    quad-group share q, differ in h=m).
// R8 post-mortem: VALU floor = silu 22us (irreducible) + einsum1-FMA 14.5us
// (moved here to MFMA) + trig 6us. Expect ~32-40us.
//
// REGISTER-PRESSURE LAW (R2/R4/R5): __launch_bounds__(256,w) caps VGPR at
// 256/w and the allocator SPILLS to meet it. Demand here ~90 -> w=2 (cap 128).
// il-loop kept rolled (unroll 1): full unroll multiplies live ranges (R4).
__global__ __launch_bounds__(256, 2)
void fcnkan_mfma(const float* __restrict__ x,
                 const float* __restrict__ W1,
                 const float* __restrict__ W2,
                 const float* __restrict__ B1,
                 const float* __restrict__ B2,
                 float* __restrict__ out) {
    const int tid  = threadIdx.x;
    const int o    = blockIdx.x;
    const int ic0  = blockIdx.y * ICHUNK;
    const int w    = tid >> 6;       // wave: b-range [w*64, w*64+64)
    const int lane = tid & 63;
    const int m    = lane & 15;      // A row / B col(h) / C col(h) within tile
    const int q    = lane >> 4;      // quad

    const short8 zero8 = {};

    // per-chunk B2 contribution (uniform; scalar loads)
    float b2c = 0.f;
    for (int il = 0; il < ICHUNK; ++il) b2c += B2[(size_t)(ic0 + il) * O_DIM + o];

    float acc[16];
    #pragma unroll
    for (int r = 0; r < 16; ++r) acc[r] = 0.f;

    #pragma unroll 1
    for (int il = 0; il < ICHUNK; ++il) {
        const int i = ic0 + il;

        // ---- A fragments (feat), quad 0 real, quads 1-3 zero ----
        short8 afrag[4];
        #pragma unroll
        for (int t = 0; t < 4; ++t) {
            float xv = x[(size_t)(w * 64 + t * 16 + m) * I_DIM + i];
            float s1 = __sinf(xv), c1 = __cosf(xv);
            float s2 = 2.f * s1 * c1, c2 = 1.f - 2.f * s1 * s1;
            float s4 = 2.f * s2 * c2, c4 = 1.f - 2.f * s2 * s2;
            short8 a;
            a[0] = bf16s(xv); a[1] = bf16s(s1); a[2] = bf16s(s2); a[3] = bf16s(s4);
            a[4] = bf16s(c1); a[5] = bf16s(c2); a[6] = bf16s(c4); a[7] = 0;
            afrag[t] = (q == 0) ? a : zero8;
        }

        // ---- B fragments (W1 rows), B1/W2 per h ----
        const size_t iobase = (size_t)i * O_DIM + o;
        const size_t w1base = iobase * (H_DIM * F_DIM);
        short8 bfrag[2];
        float  b1v[2], w2v[2];
        #pragma unroll
        for (int nt = 0; nt < 2; ++nt) {
            int h = nt * 16 + m;
            const float* wr = W1 + w1base + (size_t)h * F_DIM;
            short8 bfr;
            #pragma unroll
            for (int f = 0; f < F_DIM; ++f) bfr[f] = bf16s(wr[f]);
            bfr[7] = 0;
            bfrag[nt] = (q == 0) ? bfr : zero8;
            b1v[nt] = B1[iobase * H_DIM + h];
            w2v[nt] = W2[iobase * H_DIM + h];
        }

        // ---- MFMA (C init = B1) + silu + W2 dot ----
        #pragma unroll
        for (int nt = 0; nt < 2; ++nt) {
            float4v c0 = {b1v[nt], b1v[nt], b1v[nt], b1v[nt]};
            #pragma unroll
            for (int t = 0; t < 4; ++t) {
                float4v z = __builtin_amdgcn_mfma_f32_16x16x32_bf16(
                    afrag[t], bfrag[nt], c0, 0, 0, 0);
                #pragma unroll
                for (int r = 0; r < 4; ++r) {
                    float zz = z[r];
                    float sg = __builtin_amdgcn_rcpf(1.f + __expf(-zz));
                    acc[t * 4 + r] = fmaf(zz * sg, w2v[nt], acc[t * 4 + r]);
                }
            }
        }
    }

    // ---- h-sum: butterfly over the 16 lanes of each quad-group ----
    #pragma unroll
    for (int r = 0; r < 16; ++r) {
        float v = acc[r];
        v += __shfl_xor(v, 1, 64);
        v += __shfl_xor(v, 2, 64);
        v += __shfl_xor(v, 4, 64);
        v += __shfl_xor(v, 8, 64);
        acc[r] = v;
    }

    // lane m==0 of each quad-group writes its 16 rows
    if (m == 0) {
        #pragma unroll
        for (int t = 0; t < 4; ++t) {
            #pragma unroll
            for (int r = 0; r < 4; ++r) {
                int b = w * 64 + t * 16 + q * 4 + r;
                atomicAdd(&out[(size_t)b * O_DIM + o], acc[t * 4 + r] + b2c);
            }
        }
    }
}

extern "C" void kernel_launch(void* const* d_in, const int* in_sizes, int n_in,
                              void* d_out, int out_size, void* d_ws, size_t ws_size,
                              hipStream_t stream) {
    const float* x  = (const float*)d_in[0];
    const float* W1 = (const float*)d_in[1];
    const float* W2 = (const float*)d_in[2];
    const float* B1 = (const float*)d_in[3];
    const float* B2 = (const float*)d_in[4];
    float* out = (float*)d_out;

    hipMemsetAsync(out, 0, (size_t)out_size * sizeof(float), stream);
    dim3 grid(O_DIM, NCHUNK);
    fcnkan_mfma<<<grid, 256, 0, stream>>>(x, W1, W2, B1, B2, out);
}

// Round 10
// 122.875 us; speedup vs baseline: 5.4495x; 1.0043x over previous
//
#include <hip/hip_runtime.h>
#include <hip/hip_bf16.h>

#define B_DIM 256
#define I_DIM 128
#define O_DIM 128
#define H_DIM 32
#define F_DIM 7
#define ICHUNK 8
#define NCHUNK (I_DIM / ICHUNK)   // 16

typedef __attribute__((ext_vector_type(8))) short short8;   // 8 bf16 (4 VGPRs)
typedef __attribute__((ext_vector_type(4))) float float4v;  // MFMA C/D

__device__ inline short bf16s(float v) {
    union { __hip_bfloat16 h; short s; } u;
    u.h = __float2bfloat16(v);
    return u.s;
}

// R10 = R9 with the occupancy fix (the single change this round).
// R9 post-mortem: VALU work shrank as predicted (busy 43->37us) but wall
// stayed 62us because grid 1024 = 4 blocks/CU -> Occupancy 30%, and the
// per-il dependent loads (x scatter + W1 scalars) went uncovered.
// R10: ICHUNK 8 -> grid 2048 = 8 blocks/CU; VGPR demand measured 44 and
// LDS = 0, so with cap 64 all 32 waves/CU can be resident.
//
// REGISTER-PRESSURE LAW (R2/R4/R5): __launch_bounds__(256,w) caps VGPR at
// 256/w and the allocator SPILLS to meet it. Demand 44 (measured R9) -> w=4
// (cap 64) is safe (R3 precedent: demand 60 fit cleanly under cap 64).
// il-loop kept rolled (unroll 1): full unroll multiplies live ranges (R4).
__global__ __launch_bounds__(256, 4)
void fcnkan_mfma(const float* __restrict__ x,
                 const float* __restrict__ W1,
                 const float* __restrict__ W2,
                 const float* __restrict__ B1,
                 const float* __restrict__ B2,
                 float* __restrict__ out) {
    const int tid  = threadIdx.x;
    const int o    = blockIdx.x;
    const int ic0  = blockIdx.y * ICHUNK;
    const int w    = tid >> 6;       // wave: b-range [w*64, w*64+64)
    const int lane = tid & 63;
    const int m    = lane & 15;      // A row / B col(h) / C col(h) within tile
    const int q    = lane >> 4;      // quad

    const short8 zero8 = {};

    // per-chunk B2 contribution (uniform; scalar loads)
    float b2c = 0.f;
    for (int il = 0; il < ICHUNK; ++il) b2c += B2[(size_t)(ic0 + il) * O_DIM + o];

    float acc[16];
    #pragma unroll
    for (int r = 0; r < 16; ++r) acc[r] = 0.f;

    #pragma unroll 1
    for (int il = 0; il < ICHUNK; ++il) {
        const int i = ic0 + il;

        // ---- A fragments (feat), quad 0 real, quads 1-3 zero ----
        short8 afrag[4];
        #pragma unroll
        for (int t = 0; t < 4; ++t) {
            float xv = x[(size_t)(w * 64 + t * 16 + m) * I_DIM + i];
            float s1 = __sinf(xv), c1 = __cosf(xv);
            float s2 = 2.f * s1 * c1, c2 = 1.f - 2.f * s1 * s1;
            float s4 = 2.f * s2 * c2, c4 = 1.f - 2.f * s2 * s2;
            short8 a;
            a[0] = bf16s(xv); a[1] = bf16s(s1); a[2] = bf16s(s2); a[3] = bf16s(s4);
            a[4] = bf16s(c1); a[5] = bf16s(c2); a[6] = bf16s(c4); a[7] = 0;
            afrag[t] = (q == 0) ? a : zero8;
        }

        // ---- B fragments (W1 rows), B1/W2 per h ----
        const size_t iobase = (size_t)i * O_DIM + o;
        const size_t w1base = iobase * (H_DIM * F_DIM);
        short8 bfrag[2];
        float  b1v[2], w2v[2];
        #pragma unroll
        for (int nt = 0; nt < 2; ++nt) {
            int h = nt * 16 + m;
            const float* wr = W1 + w1base + (size_t)h * F_DIM;
            short8 bfr;
            #pragma unroll
            for (int f = 0; f < F_DIM; ++f) bfr[f] = bf16s(wr[f]);
            bfr[7] = 0;
            bfrag[nt] = (q == 0) ? bfr : zero8;
            b1v[nt] = B1[iobase * H_DIM + h];
            w2v[nt] = W2[iobase * H_DIM + h];
        }

        // ---- MFMA (C init = B1) + silu + W2 dot ----
        #pragma unroll
        for (int nt = 0; nt < 2; ++nt) {
            float4v c0 = {b1v[nt], b1v[nt], b1v[nt], b1v[nt]};
            #pragma unroll
            for (int t = 0; t < 4; ++t) {
                float4v z = __builtin_amdgcn_mfma_f32_16x16x32_bf16(
                    afrag[t], bfrag[nt], c0, 0, 0, 0);
                #pragma unroll
                for (int r = 0; r < 4; ++r) {
                    float zz = z[r];
                    float sg = __builtin_amdgcn_rcpf(1.f + __expf(-zz));
                    acc[t * 4 + r] = fmaf(zz * sg, w2v[nt], acc[t * 4 + r]);
                }
            }
        }
    }

    // ---- h-sum: butterfly over the 16 lanes of each quad-group ----
    #pragma unroll
    for (int r = 0; r < 16; ++r) {
        float v = acc[r];
        v += __shfl_xor(v, 1, 64);
        v += __shfl_xor(v, 2, 64);
        v += __shfl_xor(v, 4, 64);
        v += __shfl_xor(v, 8, 64);
        acc[r] = v;
    }

    // lane m==0 of each quad-group writes its 16 rows
    if (m == 0) {
        #pragma unroll
        for (int t = 0; t < 4; ++t) {
            #pragma unroll
            for (int r = 0; r < 4; ++r) {
                int b = w * 64 + t * 16 + q * 4 + r;
                atomicAdd(&out[(size_t)b * O_DIM + o], acc[t * 4 + r] + b2c);
            }
        }
    }
}

extern "C" void kernel_launch(void* const* d_in, const int* in_sizes, int n_in,
                              void* d_out, int out_size, void* d_ws, size_t ws_size,
                              hipStream_t stream) {
    const float* x  = (const float*)d_in[0];
    const float* W1 = (const float*)d_in[1];
    const float* W2 = (const float*)d_in[2];
    const float* B1 = (const float*)d_in[3];
    const float* B2 = (const float*)d_in[4];
    float* out = (float*)d_out;

    hipMemsetAsync(out, 0, (size_t)out_size * sizeof(float), stream);
    dim3 grid(O_DIM, NCHUNK);
    fcnkan_mfma<<<grid, 256, 0, stream>>>(x, W1, W2, B1, B2, out);
}

// Round 11
// 107.440 us; speedup vs baseline: 6.2324x; 1.1437x over previous
//
#include <hip/hip_runtime.h>
#include <hip/hip_bf16.h>

#define B_DIM 256
#define I_DIM 128
#define O_DIM 128
#define H_DIM 32
#define F_DIM 7
#define ICHUNK 8
#define NCHUNK (I_DIM / ICHUNK)   // 16

typedef __attribute__((ext_vector_type(8))) short short8;   // 8 bf16 (4 VGPRs)
typedef __attribute__((ext_vector_type(4))) float float4v;  // MFMA C/D

__device__ inline short bf16s(float v) {
    union { __hip_bfloat16 h; short s; } u;
    u.h = __float2bfloat16(v);
    return u.s;
}

// R11: fully LDS-resident K-loop.
// R10 post-mortem: doubling blocks/CU changed nothing (62us, VALUBusy 59%) ->
// the stall is per-il HBM-latency W1 loads + scattered x loads that every
// resident wave hits simultaneously; TLP can't fix it. Fix: one staging
// phase (single barrier) moves EVERYTHING into LDS, bf16-pre-packed:
//  - feat[il][b]: 16B A-row per (il,b). Trig computed once per b (kills the
//    4x quad-redundant trig of R9/R10: 16 -> 4 sin-insts/block/il).
//  - w1s[il][h]: 16B bf16 B-row (slot7=0) -> in-loop B-frag = ONE
//    ds_read_b128, zero conversions in the loop.
//  - A-frag = ONE ds_read_b128; 16B lane stride = 2-way bank alias = free
//    (m136). Only B is quad-zeroed (A garbage x B=0 is fine): 8 cndmask/il.
// LDS 39KB -> 4 blocks/CU (R10 showed >4 doesn't materialize anyway).
//
// REGISTER-PRESSURE LAW (R2/R4/R5): __launch_bounds__(256,w) hard-caps VGPR
// at 256/w and the allocator SPILLS to meet it. (256,2)=cap 128 >> demand
// (~60): no forced spill; LDS governs occupancy, not the VGPR cap.
// il-loop kept rolled (unroll 1): full unroll multiplies live ranges (R4).
__global__ __launch_bounds__(256, 2)
void fcnkan_mfma(const float* __restrict__ x,
                 const float* __restrict__ W1,
                 const float* __restrict__ W2,
                 const float* __restrict__ B1,
                 const float* __restrict__ B2,
                 float* __restrict__ out) {
    __shared__ __align__(16) short feat_s[ICHUNK * B_DIM * 8];   // 32 KB
    __shared__ __align__(16) short w1_s[ICHUNK * H_DIM * 8];     // 4 KB
    __shared__ float b1_s[ICHUNK * H_DIM];                       // 1 KB
    __shared__ float w2_s[ICHUNK * H_DIM];                       // 1 KB

    const int tid  = threadIdx.x;
    const int o    = blockIdx.x;
    const int ic0  = blockIdx.y * ICHUNK;
    const int w    = tid >> 6;       // wave: b-range [w*64, w*64+64)
    const int lane = tid & 63;
    const int m    = lane & 15;      // row/col within 16x16 tile
    const int q    = lane >> 4;      // quad

    const short8 zero8 = {};

    // ---- stage A: own x row, trig once per (b, il), bf16-pack ----
    {
        const float4* xp = reinterpret_cast<const float4*>(x + (size_t)tid * I_DIM + ic0);
        float4 x0 = xp[0], x1 = xp[1];
        float xr[8] = {x0.x, x0.y, x0.z, x0.w, x1.x, x1.y, x1.z, x1.w};
        #pragma unroll
        for (int il = 0; il < ICHUNK; ++il) {
            float xv = xr[il];
            float s1 = __sinf(xv), c1 = __cosf(xv);
            float s2 = 2.f * s1 * c1, c2 = 1.f - 2.f * s1 * s1;
            float s4 = 2.f * s2 * c2, c4 = 1.f - 2.f * s2 * s2;
            short8 a;
            a[0] = bf16s(xv); a[1] = bf16s(s1); a[2] = bf16s(s2); a[3] = bf16s(s4);
            a[4] = bf16s(c1); a[5] = bf16s(c2); a[6] = bf16s(c4); a[7] = 0;
            *reinterpret_cast<short8*>(feat_s + (il * B_DIM + tid) * 8) = a;
        }
    }
    // ---- stage B: thread tid <-> (il = tid>>5, h = tid&31), one W1 row ----
    {
        int il = tid >> 5, h = tid & 31;
        size_t iobase = (size_t)(ic0 + il) * O_DIM + o;
        const float* wr = W1 + iobase * (H_DIM * F_DIM) + h * F_DIM;
        short8 bfr;
        #pragma unroll
        for (int f = 0; f < F_DIM; ++f) bfr[f] = bf16s(wr[f]);
        bfr[7] = 0;
        *reinterpret_cast<short8*>(w1_s + tid * 8) = bfr;
        b1_s[tid] = B1[iobase * H_DIM + h];
        w2_s[tid] = W2[iobase * H_DIM + h];
    }
    __syncthreads();

    float acc[16];
    #pragma unroll
    for (int r = 0; r < 16; ++r) acc[r] = 0.f;

    #pragma unroll 1
    for (int il = 0; il < ICHUNK; ++il) {
        const short8* fS = reinterpret_cast<const short8*>(feat_s) + il * B_DIM;
        const short8* wS = reinterpret_cast<const short8*>(w1_s) + il * H_DIM;

        short8 afrag[4];
        #pragma unroll
        for (int t = 0; t < 4; ++t)
            afrag[t] = fS[w * 64 + t * 16 + m];          // ds_read_b128

        short8 bfrag[2];
        float  b1v[2], w2v[2];
        #pragma unroll
        for (int nt = 0; nt < 2; ++nt) {
            int h = nt * 16 + m;
            short8 b = wS[h];                            // ds_read_b128
            bfrag[nt] = (q == 0) ? b : zero8;            // only B quad-zeroed
            b1v[nt] = b1_s[il * H_DIM + h];
            w2v[nt] = w2_s[il * H_DIM + h];
        }

        #pragma unroll
        for (int nt = 0; nt < 2; ++nt) {
            float4v c0 = {b1v[nt], b1v[nt], b1v[nt], b1v[nt]};
            #pragma unroll
            for (int t = 0; t < 4; ++t) {
                float4v z = __builtin_amdgcn_mfma_f32_16x16x32_bf16(
                    afrag[t], bfrag[nt], c0, 0, 0, 0);
                #pragma unroll
                for (int r = 0; r < 4; ++r) {
                    float zz = z[r];
                    float sg = __builtin_amdgcn_rcpf(1.f + __expf(-zz));
                    acc[t * 4 + r] = fmaf(zz * sg, w2v[nt], acc[t * 4 + r]);
                }
            }
        }
    }

    // ---- h-sum: butterfly over the 16 lanes of each quad-group ----
    #pragma unroll
    for (int r = 0; r < 16; ++r) {
        float v = acc[r];
        v += __shfl_xor(v, 1, 64);
        v += __shfl_xor(v, 2, 64);
        v += __shfl_xor(v, 4, 64);
        v += __shfl_xor(v, 8, 64);
        acc[r] = v;
    }

    // per-chunk B2 contribution (uniform)
    float b2c = 0.f;
    for (int il = 0; il < ICHUNK; ++il) b2c += B2[(size_t)(ic0 + il) * O_DIM + o];

    // lane m==0 of each quad-group writes its 16 rows
    if (m == 0) {
        #pragma unroll
        for (int t = 0; t < 4; ++t) {
            #pragma unroll
            for (int r = 0; r < 4; ++r) {
                int b = w * 64 + t * 16 + q * 4 + r;
                atomicAdd(&out[(size_t)b * O_DIM + o], acc[t * 4 + r] + b2c);
            }
        }
    }
}

extern "C" void kernel_launch(void* const* d_in, const int* in_sizes, int n_in,
                              void* d_out, int out_size, void* d_ws, size_t ws_size,
                              hipStream_t stream) {
    const float* x  = (const float*)d_in[0];
    const float* W1 = (const float*)d_in[1];
    const float* W2 = (const float*)d_in[2];
    const float* B1 = (const float*)d_in[3];
    const float* B2 = (const float*)d_in[4];
    float* out = (float*)d_out;

    hipMemsetAsync(out, 0, (size_t)out_size * sizeof(float), stream);
    dim3 grid(O_DIM, NCHUNK);
    fcnkan_mfma<<<grid, 256, 0, stream>>>(x, W1, W2, B1, B2, out);
}